// Round 4
// baseline (285.953 us; speedup 1.0000x reference)
//
#include <hip/hip_runtime.h>

// weights_i = exp(F_i·w) / segsum_{pid}(exp(F·w))
//   F: [N,128] fp32 (1.024 GB — the HBM floor), w: [128], pid: [N] int32,
//   out: [N] fp32.
//
// R3b: split the scatter-atomics OUT of the streaming kernel to isolate cost.
//   K1 logit_kernel : pure stream (16 rows/wave/iter, 8x float4 loads in
//                     flight, select-merge shuffle tree), nontemporal F.
//   K2 segsum_kernel: logit+pid (16 MB) -> 2M atomicAdd into part[S].
//   K3 weights_kernel: out = logit / part[pid], float4-vectorized.

typedef float f32x4 __attribute__((ext_vector_type(4)));

__global__ void logit_kernel(const f32x4* __restrict__ F4,
                             const float* __restrict__ w,
                             float* __restrict__ logit,
                             int nrows) {
    const int lane = threadIdx.x & 63;
    const int l32  = lane & 31;
    const int half = lane >> 5;
    const int wave  = (blockIdx.x * blockDim.x + threadIdx.x) >> 6;
    const int nwave = (gridDim.x * blockDim.x) >> 6;

    const f32x4 wf = reinterpret_cast<const f32x4*>(w)[l32];

    const int ntile = nrows / 16;
    const int nmain = ntile * 16;

    for (int t = wave; t < ntile; t += nwave) {
        const int r = t * 16;

        // 8 independent 1KB wave-loads: rows r .. r+15 (read-once -> nt)
        f32x4 f[8];
        #pragma unroll
        for (int j = 0; j < 8; ++j)
            f[j] = __builtin_nontemporal_load(
                &F4[(size_t)(r + 2 * j + half) * 32 + l32]);

        float s[8];
        #pragma unroll
        for (int j = 0; j < 8; ++j)
            s[j] = f[j].x * wf.x + f[j].y * wf.y + f[j].z * wf.z + f[j].w * wf.w;

        // select-merge reduction within each 32-lane half:
        // 16 shuffles reduce 8 rows/half -> 8 owner lanes/half
        float m[4];
        #pragma unroll
        for (int j = 0; j < 4; ++j) {
            float u = s[2*j]   + __shfl_xor(s[2*j],   16, 64);
            float v = s[2*j+1] + __shfl_xor(s[2*j+1], 16, 64);
            m[j] = (l32 & 16) ? v : u;
        }
        float n[2];
        #pragma unroll
        for (int j = 0; j < 2; ++j) {
            float u = m[2*j]   + __shfl_xor(m[2*j],   8, 64);
            float v = m[2*j+1] + __shfl_xor(m[2*j+1], 8, 64);
            n[j] = (l32 & 8) ? v : u;
        }
        float u = n[0] + __shfl_xor(n[0], 4, 64);
        float v = n[1] + __shfl_xor(n[1], 4, 64);
        float tt = (l32 & 4) ? v : u;
        tt += __shfl_xor(tt, 2, 64);
        tt += __shfl_xor(tt, 1, 64);

        if ((l32 & 3) == 0) {
            const int jidx = ((l32 >> 2) & 1) * 4 + ((l32 >> 3) & 1) * 2 +
                             ((l32 >> 4) & 1);
            const int row = r + 2 * jidx + half;
            logit[row] = expf(tt);
        }
    }

    // tail rows
    for (int r = nmain + wave * 2; r < nrows; r += nwave * 2) {
        const int row = r + half;
        if (row < nrows) {
            f32x4 f = F4[(size_t)row * 32 + l32];
            float s = f.x * wf.x + f.y * wf.y + f.z * wf.z + f.w * wf.w;
            #pragma unroll
            for (int o = 16; o; o >>= 1) s += __shfl_xor(s, o, 64);
            if (l32 == 0) logit[row] = expf(s);
        }
    }
}

__global__ void segsum_kernel(const float4* __restrict__ logit4,
                              const int4* __restrict__ pid4,
                              float* __restrict__ part,
                              int nvec,
                              const float* __restrict__ logit,
                              const int* __restrict__ pid,
                              int n) {
    int i = blockIdx.x * blockDim.x + threadIdx.x;
    const int stride = gridDim.x * blockDim.x;
    for (; i < nvec; i += stride) {
        float4 lg = logit4[i];
        int4 p = pid4[i];
        atomicAdd(&part[p.x], lg.x);
        atomicAdd(&part[p.y], lg.y);
        atomicAdd(&part[p.z], lg.z);
        atomicAdd(&part[p.w], lg.w);
    }
    if (blockIdx.x == 0 && threadIdx.x == 0) {
        for (int j = nvec * 4; j < n; ++j) atomicAdd(&part[pid[j]], logit[j]);
    }
}

__global__ void weights_kernel(const float4* __restrict__ logit4,
                               const int4* __restrict__ pid4,
                               const float* __restrict__ part,
                               float4* __restrict__ out4,
                               int nvec,
                               const float* __restrict__ logit,
                               const int* __restrict__ pid,
                               float* __restrict__ out,
                               int n) {
    int i = blockIdx.x * blockDim.x + threadIdx.x;
    const int stride = gridDim.x * blockDim.x;
    for (; i < nvec; i += stride) {
        float4 lg = logit4[i];
        int4 p = pid4[i];
        float4 o;
        o.x = lg.x / part[p.x];
        o.y = lg.y / part[p.y];
        o.z = lg.z / part[p.z];
        o.w = lg.w / part[p.w];
        out4[i] = o;
    }
    if (blockIdx.x == 0 && threadIdx.x == 0) {
        for (int j = nvec * 4; j < n; ++j) out[j] = logit[j] / part[pid[j]];
    }
}

extern "C" void kernel_launch(void* const* d_in, const int* in_sizes, int n_in,
                              void* d_out, int out_size, void* d_ws, size_t ws_size,
                              hipStream_t stream) {
    const float* features = (const float*)d_in[0];   // [N,128]
    const float* w        = (const float*)d_in[1];   // [128]
    const int*   pid      = (const int*)d_in[2];     // [N]

    const int N = in_sizes[2];
    const int S = in_sizes[3];

    float* logit = (float*)d_ws;            // N floats
    float* part  = logit + N;               // S floats
    float* out   = (float*)d_out;

    (void)hipMemsetAsync(part, 0, (size_t)S * sizeof(float), stream);

    // K1: pure streaming dot+exp (2048 blocks x 256 = 32 waves/CU)
    logit_kernel<<<dim3(2048), dim3(256), 0, stream>>>(
        (const f32x4*)features, w, logit, N);

    const int nvec = N / 4;
    int blocks = (nvec + 255) / 256;
    if (blocks > 2048) blocks = 2048;

    // K2: isolated scatter-atomic segment sum
    segsum_kernel<<<dim3(blocks), dim3(256), 0, stream>>>(
        (const float4*)logit, (const int4*)pid, part, nvec, logit, pid, N);

    // K3: vectorized divide+gather
    weights_kernel<<<dim3(blocks), dim3(256), 0, stream>>>(
        (const float4*)logit, (const int4*)pid, part, (float4*)out, nvec,
        logit, pid, out, N);
}

// Round 5
// 208.008 us; speedup vs baseline: 1.3747x; 1.3747x over previous
//
#include <hip/hip_runtime.h>

// weights_i = exp(F_i·w) / segsum_{pid}(exp(F·w))
//   F: [N,128] fp32 (1.024 GB — the HBM floor), w: [128], pid: [N] int32,
//   out: [N] fp32.
//
// R5: fused structure (R2, best=230us) + two fixes:
//   1. unsafeAtomicAdd -> HW global_atomic_add_f32 (fire-and-forget).
//      Plain atomicAdd(float*) lowers to a CAS retry loop on AMD without
//      -munsafe-fp-atomics; with ~20 collisions/bin over 2M ops that CAS
//      tax is the suspected ~50-90us of R2/R3b.
//   2. nontemporal F loads (1 GB single-use stream, skip L2 allocation).

typedef float f32x4 __attribute__((ext_vector_type(4)));

__global__ void logit_partition_kernel(const f32x4* __restrict__ F4,
                                       const float* __restrict__ w,
                                       const int* __restrict__ pid,
                                       float* __restrict__ logit,
                                       float* __restrict__ part,
                                       int nrows) {
    const int lane = threadIdx.x & 63;
    const int l32  = lane & 31;
    const int half = lane >> 5;
    const int wave  = (blockIdx.x * blockDim.x + threadIdx.x) >> 6;
    const int nwave = (gridDim.x * blockDim.x) >> 6;

    // lane l32 holds w[4*l32 .. 4*l32+3]
    const f32x4 wf = reinterpret_cast<const f32x4*>(w)[l32];

    const int ntile = nrows / 16;
    const int nmain = ntile * 16;

    for (int t = wave; t < ntile; t += nwave) {
        const int r = t * 16;

        // 8 independent 1KB wave-loads: rows r .. r+15 (read-once -> nt)
        f32x4 f[8];
        #pragma unroll
        for (int j = 0; j < 8; ++j)
            f[j] = __builtin_nontemporal_load(
                &F4[(size_t)(r + 2 * j + half) * 32 + l32]);

        float s[8];
        #pragma unroll
        for (int j = 0; j < 8; ++j)
            s[j] = f[j].x * wf.x + f[j].y * wf.y + f[j].z * wf.z + f[j].w * wf.w;

        // select-merge reduction within each 32-lane half:
        // 16 shuffles reduce 16 rows -> 16 owner lanes
        float m[4];
        #pragma unroll
        for (int j = 0; j < 4; ++j) {
            float u = s[2*j]   + __shfl_xor(s[2*j],   16, 64);
            float v = s[2*j+1] + __shfl_xor(s[2*j+1], 16, 64);
            m[j] = (l32 & 16) ? v : u;
        }
        float n[2];
        #pragma unroll
        for (int j = 0; j < 2; ++j) {
            float u = m[2*j]   + __shfl_xor(m[2*j],   8, 64);
            float v = m[2*j+1] + __shfl_xor(m[2*j+1], 8, 64);
            n[j] = (l32 & 8) ? v : u;
        }
        float u = n[0] + __shfl_xor(n[0], 4, 64);
        float v = n[1] + __shfl_xor(n[1], 4, 64);
        float tt = (l32 & 4) ? v : u;
        tt += __shfl_xor(tt, 2, 64);
        tt += __shfl_xor(tt, 1, 64);

        if ((l32 & 3) == 0) {
            const int jidx = ((l32 >> 2) & 1) * 4 + ((l32 >> 3) & 1) * 2 +
                             ((l32 >> 4) & 1);
            const int row = r + 2 * jidx + half;
            float lg = expf(tt);
            logit[row] = lg;
            unsafeAtomicAdd(&part[pid[row]], lg);  // HW global_atomic_add_f32
        }
    }

    // tail rows (empty for N divisible by 16)
    for (int r = nmain + wave * 2; r < nrows; r += nwave * 2) {
        const int row = r + half;
        if (row < nrows) {
            f32x4 f = F4[(size_t)row * 32 + l32];
            float s = f.x * wf.x + f.y * wf.y + f.z * wf.z + f.w * wf.w;
            #pragma unroll
            for (int o = 16; o; o >>= 1) s += __shfl_xor(s, o, 64);
            if (l32 == 0) {
                float lg = expf(s);
                logit[row] = lg;
                unsafeAtomicAdd(&part[pid[row]], lg);
            }
        }
    }
}

__global__ void weights_kernel(const float4* __restrict__ logit4,
                               const int4* __restrict__ pid4,
                               const float* __restrict__ part,
                               float4* __restrict__ out4,
                               int nvec,
                               const float* __restrict__ logit,
                               const int* __restrict__ pid,
                               float* __restrict__ out,
                               int n) {
    int i = blockIdx.x * blockDim.x + threadIdx.x;
    const int stride = gridDim.x * blockDim.x;
    for (; i < nvec; i += stride) {
        float4 lg = logit4[i];
        int4 p = pid4[i];
        float4 o;
        o.x = lg.x / part[p.x];
        o.y = lg.y / part[p.y];
        o.z = lg.z / part[p.z];
        o.w = lg.w / part[p.w];
        out4[i] = o;
    }
    if (blockIdx.x == 0 && threadIdx.x == 0) {
        for (int j = nvec * 4; j < n; ++j) out[j] = logit[j] / part[pid[j]];
    }
}

extern "C" void kernel_launch(void* const* d_in, const int* in_sizes, int n_in,
                              void* d_out, int out_size, void* d_ws, size_t ws_size,
                              hipStream_t stream) {
    const float* features = (const float*)d_in[0];   // [N,128]
    const float* w        = (const float*)d_in[1];   // [128]
    const int*   pid      = (const int*)d_in[2];     // [N]

    const int N = in_sizes[2];
    const int S = in_sizes[3];

    float* logit = (float*)d_ws;            // N floats
    float* part  = logit + N;               // S floats
    float* out   = (float*)d_out;

    // re-zero partition bins every call (graph-replay determinism)
    (void)hipMemsetAsync(part, 0, (size_t)S * sizeof(float), stream);

    // K1: fused stream dot+exp+scatter (2048 blocks x 256 = 32 waves/CU)
    logit_partition_kernel<<<dim3(2048), dim3(256), 0, stream>>>(
        (const f32x4*)features, w, pid, logit, part, N);

    // K2: vectorized divide+gather
    {
        const int nvec = N / 4;
        int blocks = (nvec + 255) / 256;
        if (blocks > 2048) blocks = 2048;
        weights_kernel<<<dim3(blocks), dim3(256), 0, stream>>>(
            (const float4*)logit, (const int4*)pid, part, (float4*)out, nvec,
            logit, pid, out, N);
    }
}